// Round 5
// baseline (368.779 us; speedup 1.0000x reference)
//
#include <hip/hip_runtime.h>

#define NN 50000
#define NE 800000
#define NG 64
#define DPART (NN / 8)

// ============================ helpers ============================

__device__ __forceinline__ float4 add4(float4 a, float4 b) {
  return make_float4(a.x + b.x, a.y + b.y, a.z + b.z, a.w + b.w);
}

__device__ __forceinline__ unsigned int bfpack2(float lo, float hi) {
  unsigned int a = __float_as_uint(lo);
  unsigned int b = __float_as_uint(hi);
  a = (a + 0x7FFFu + ((a >> 16) & 1u)) >> 16;  // RNE bf16
  b = (b + 0x7FFFu + ((b >> 16) & 1u)) >> 16;
  return a | (b << 16);
}

// dot of 64-elem register row with LDS column (broadcast reads)
__device__ __forceinline__ float dot64(const float4* __restrict__ xr4,
                                       const float* __restrict__ w) {
  float acc = 0.f;
#pragma unroll
  for (int k4 = 0; k4 < 16; ++k4) {
    float4 wv = *(const float4*)(w + k4 * 4);
    float4 x = xr4[k4];
    acc += x.x * wv.x + x.y * wv.y + x.z * wv.z + x.w * wv.w;
  }
  return acc;
}

// ============================ CSR build ============================

__global__ void hist_kernel(const int* __restrict__ ei, int* __restrict__ deg) {
  int e = blockIdx.x * blockDim.x + threadIdx.x;
  if (e < NE) atomicAdd(&deg[ei[NE + e]], 1);
}

__global__ void scan1_kernel(const int* __restrict__ deg, int* __restrict__ rowptr,
                             int* __restrict__ bsums) {
  __shared__ int tile[256];
  int t = threadIdx.x, gid = blockIdx.x * 256 + t;
  int v = (gid < NN) ? deg[gid] : 0;
  tile[t] = v;
  __syncthreads();
  for (int off = 1; off < 256; off <<= 1) {
    int u = (t >= off) ? tile[t - off] : 0;
    __syncthreads();
    tile[t] += u;
    __syncthreads();
  }
  if (gid < NN) rowptr[gid] = tile[t] - v;
  if (t == 255) bsums[blockIdx.x] = tile[t];
}

__global__ void scan2_kernel(int* __restrict__ bsums, int nb) {
  __shared__ int tile[256];
  int t = threadIdx.x;
  int v = (t < nb) ? bsums[t] : 0;
  tile[t] = v;
  __syncthreads();
  for (int off = 1; off < 256; off <<= 1) {
    int u = (t >= off) ? tile[t - off] : 0;
    __syncthreads();
    tile[t] += u;
    __syncthreads();
  }
  if (t < nb) bsums[t] = tile[t] - v;
}

__global__ void scan3_kernel(int* __restrict__ rowptr, const int* __restrict__ bsums,
                             int* __restrict__ cursor) {
  int gid = blockIdx.x * 256 + threadIdx.x;
  if (gid < NN) {
    int r = rowptr[gid] + bsums[blockIdx.x];
    rowptr[gid] = r;
    cursor[gid] = r;
  } else if (gid == NN) {
    rowptr[NN] = NE;
  }
}

// XCD-partitioned scatter (kills write amplification; correct under any mapping)
__global__ __launch_bounds__(256) void scatter_xcd(const int* __restrict__ ei,
                                                   int* __restrict__ cursor,
                                                   int* __restrict__ srcs) {
  int g = blockIdx.x & 7;
  int bid = blockIdx.x >> 3;
  int nb = gridDim.x >> 3;
  int lo = g * DPART, hi = lo + DPART;
  int stride = nb * 256;
  for (int e = bid * 256 + threadIdx.x; e < NE; e += stride) {
    int d = ei[NE + e];
    if (d >= lo && d < hi) {
      int pos = atomicAdd(&cursor[d], 1);
      srcs[pos] = ei[e];
    }
  }
}

// ============================ node GEMMs (row-per-thread) ============================
// a_tab[n][c] = sum_k feat[n][k]*W[k][c]          (f32)
// b_tab[n][c] = sum_k feat[n][k]*W[64+k][c]       (bf16 packed)
__global__ __launch_bounds__(128, 1) void transform_dual(const float* __restrict__ feat,
                                                         const float* __restrict__ W,
                                                         float* __restrict__ a_tab,
                                                         unsigned int* __restrict__ b_tab) {
  __shared__ float wt[128 * 64];  // wt[c*64+k] = W[(c>=64)*64 + k][c&63]
  int t = threadIdx.x;
  for (int i = t; i < 8192; i += 128) {
    int c = i >> 6, k = i & 63;
    wt[i] = W[((c >> 6) * 64 + k) * 64 + (c & 63)];
  }
  __syncthreads();
  int node = blockIdx.x * 128 + t;
  if (node >= NN) return;

  float4 xr4[16];
  const float4* f4 = (const float4*)(feat + (size_t)node * 64);
#pragma unroll
  for (int i = 0; i < 16; ++i) xr4[i] = f4[i];

  float4* a4 = (float4*)(a_tab + (size_t)node * 64);
  for (int cg = 0; cg < 16; ++cg) {
    float d0 = dot64(xr4, &wt[(cg * 4 + 0) * 64]);
    float d1 = dot64(xr4, &wt[(cg * 4 + 1) * 64]);
    float d2 = dot64(xr4, &wt[(cg * 4 + 2) * 64]);
    float d3 = dot64(xr4, &wt[(cg * 4 + 3) * 64]);
    a4[cg] = make_float4(d0, d1, d2, d3);
  }
  uint2* bp = (uint2*)b_tab + (size_t)node * 8;  // 64 bf16 = 8 uint2... (16 B gran below)
  // row = 64 bf16 = 32 uints = 16 uint2
  bp = (uint2*)((char*)b_tab + (size_t)node * 128);
  for (int cg = 0; cg < 16; ++cg) {
    float d0 = dot64(xr4, &wt[(64 + cg * 4 + 0) * 64]);
    float d1 = dot64(xr4, &wt[(64 + cg * 4 + 1) * 64]);
    float d2 = dot64(xr4, &wt[(64 + cg * 4 + 2) * 64]);
    float d3 = dot64(xr4, &wt[(64 + cg * 4 + 3) * 64]);
    bp[cg] = make_uint2(bfpack2(d0, d1), bfpack2(d2, d3));
  }
}

// fused: h = relu(agg@W2 + cnt*b2)  (registers only), then a/b tables from h@W1next
__global__ __launch_bounds__(128, 1) void transform_fused(const float* __restrict__ agg,
                                                          const float* __restrict__ W2,
                                                          const float* __restrict__ b2,
                                                          const int* __restrict__ deg,
                                                          const float* __restrict__ W1,
                                                          float* __restrict__ a_tab,
                                                          unsigned int* __restrict__ b_tab) {
  __shared__ float wt2[64 * 64];   // wt2[c*64+k] = W2[k][c]
  __shared__ float wt1[128 * 64];  // wt1[c*64+k] = W1[(c>=64)*64+k][c&63]
  int t = threadIdx.x;
  for (int i = t; i < 4096; i += 128) {
    int c = i >> 6, k = i & 63;
    wt2[i] = W2[k * 64 + c];
  }
  for (int i = t; i < 8192; i += 128) {
    int c = i >> 6, k = i & 63;
    wt1[i] = W1[((c >> 6) * 64 + k) * 64 + (c & 63)];
  }
  __syncthreads();
  int node = blockIdx.x * 128 + t;
  if (node >= NN) return;

  float4 xr4[16];
  const float4* f4 = (const float4*)(agg + (size_t)node * 64);
#pragma unroll
  for (int i = 0; i < 16; ++i) xr4[i] = f4[i];
  float cnt = (float)(deg[node] + 1);

  float4 hr4[16];
  const float4* b24 = (const float4*)b2;
  for (int cg = 0; cg < 16; ++cg) {
    float4 bv = b24[cg];
    float d0 = dot64(xr4, &wt2[(cg * 4 + 0) * 64]) + cnt * bv.x;
    float d1 = dot64(xr4, &wt2[(cg * 4 + 1) * 64]) + cnt * bv.y;
    float d2 = dot64(xr4, &wt2[(cg * 4 + 2) * 64]) + cnt * bv.z;
    float d3 = dot64(xr4, &wt2[(cg * 4 + 3) * 64]) + cnt * bv.w;
    hr4[cg] = make_float4(fmaxf(d0, 0.f), fmaxf(d1, 0.f), fmaxf(d2, 0.f), fmaxf(d3, 0.f));
  }

  float4* a4 = (float4*)(a_tab + (size_t)node * 64);
  for (int cg = 0; cg < 16; ++cg) {
    float d0 = dot64(hr4, &wt1[(cg * 4 + 0) * 64]);
    float d1 = dot64(hr4, &wt1[(cg * 4 + 1) * 64]);
    float d2 = dot64(hr4, &wt1[(cg * 4 + 2) * 64]);
    float d3 = dot64(hr4, &wt1[(cg * 4 + 3) * 64]);
    a4[cg] = make_float4(d0, d1, d2, d3);
  }
  uint2* bp = (uint2*)((char*)b_tab + (size_t)node * 128);
  for (int cg = 0; cg < 16; ++cg) {
    float d0 = dot64(hr4, &wt1[(64 + cg * 4 + 0) * 64]);
    float d1 = dot64(hr4, &wt1[(64 + cg * 4 + 1) * 64]);
    float d2 = dot64(hr4, &wt1[(64 + cg * 4 + 2) * 64]);
    float d3 = dot64(hr4, &wt1[(64 + cg * 4 + 3) * 64]);
    bp[cg] = make_uint2(bfpack2(d0, d1), bfpack2(d2, d3));
  }
}

// single: out = relu(agg@W2 + cnt*b2), in-place safe (row-per-thread)
__global__ __launch_bounds__(128, 1) void transform_single(const float* __restrict__ agg,
                                                           const float* __restrict__ W2,
                                                           const float* __restrict__ b2,
                                                           const int* __restrict__ deg,
                                                           float* __restrict__ out) {
  __shared__ float wt2[64 * 64];
  int t = threadIdx.x;
  for (int i = t; i < 4096; i += 128) {
    int c = i >> 6, k = i & 63;
    wt2[i] = W2[k * 64 + c];
  }
  __syncthreads();
  int node = blockIdx.x * 128 + t;
  if (node >= NN) return;

  float4 xr4[16];
  const float4* f4 = (const float4*)(agg + (size_t)node * 64);
#pragma unroll
  for (int i = 0; i < 16; ++i) xr4[i] = f4[i];
  float cnt = (float)(deg[node] + 1);

  float4* o4 = (float4*)(out + (size_t)node * 64);
  const float4* b24 = (const float4*)b2;
  for (int cg = 0; cg < 16; ++cg) {
    float4 bv = b24[cg];
    float d0 = dot64(xr4, &wt2[(cg * 4 + 0) * 64]) + cnt * bv.x;
    float d1 = dot64(xr4, &wt2[(cg * 4 + 1) * 64]) + cnt * bv.y;
    float d2 = dot64(xr4, &wt2[(cg * 4 + 2) * 64]) + cnt * bv.z;
    float d3 = dot64(xr4, &wt2[(cg * 4 + 3) * 64]) + cnt * bv.w;
    o4[cg] = make_float4(fmaxf(d0, 0.f), fmaxf(d1, 0.f), fmaxf(d2, 0.f), fmaxf(d3, 0.f));
  }
}

// ============================ edge aggregation ============================
// agg[n][c] = sum over in-edges+self of relu(a[n][c]+b1[c]+b_bf16[src][c])
// Wave: 8 edge-slots x 8 lanes; lane holds 8 channels.
__global__ __launch_bounds__(256) void edge_agg(const float* __restrict__ a_tab,
                                                const unsigned int* __restrict__ b_tab,
                                                const int* __restrict__ rowptr,
                                                const int* __restrict__ srcs,
                                                const float* __restrict__ b1,
                                                float* __restrict__ agg) {
  int node = blockIdx.x * 4 + (threadIdx.x >> 6);
  if (node >= NN) return;
  int lane = threadIdx.x & 63;
  int slot = lane >> 3;
  int c8 = lane & 7;

  const float4* a4 = (const float4*)a_tab;
  const float4* b14 = (const float4*)b1;
  const uint4* bt = (const uint4*)b_tab;  // row = 8 uint4

  float4 an0 = add4(a4[(size_t)node * 16 + c8 * 2], b14[c8 * 2]);
  float4 an1 = add4(a4[(size_t)node * 16 + c8 * 2 + 1], b14[c8 * 2 + 1]);

  float4 acc0 = make_float4(0.f, 0.f, 0.f, 0.f);
  float4 acc1 = make_float4(0.f, 0.f, 0.f, 0.f);

  if (slot == 0) {  // self loop
    uint4 bv = bt[(size_t)node * 8 + c8];
    acc0.x = fmaxf(an0.x + __uint_as_float(bv.x << 16), 0.f);
    acc0.y = fmaxf(an0.y + __uint_as_float(bv.x & 0xFFFF0000u), 0.f);
    acc0.z = fmaxf(an0.z + __uint_as_float(bv.y << 16), 0.f);
    acc0.w = fmaxf(an0.w + __uint_as_float(bv.y & 0xFFFF0000u), 0.f);
    acc1.x = fmaxf(an1.x + __uint_as_float(bv.z << 16), 0.f);
    acc1.y = fmaxf(an1.y + __uint_as_float(bv.z & 0xFFFF0000u), 0.f);
    acc1.z = fmaxf(an1.z + __uint_as_float(bv.w << 16), 0.f);
    acc1.w = fmaxf(an1.w + __uint_as_float(bv.w & 0xFFFF0000u), 0.f);
  }

  int s0 = rowptr[node], s1 = rowptr[node + 1];
  for (int e = s0 + slot; e < s1; e += 8) {
    int s = srcs[e];
    uint4 bv = bt[(size_t)s * 8 + c8];
    acc0.x += fmaxf(an0.x + __uint_as_float(bv.x << 16), 0.f);
    acc0.y += fmaxf(an0.y + __uint_as_float(bv.x & 0xFFFF0000u), 0.f);
    acc0.z += fmaxf(an0.z + __uint_as_float(bv.y << 16), 0.f);
    acc0.w += fmaxf(an0.w + __uint_as_float(bv.y & 0xFFFF0000u), 0.f);
    acc1.x += fmaxf(an1.x + __uint_as_float(bv.z << 16), 0.f);
    acc1.y += fmaxf(an1.y + __uint_as_float(bv.z & 0xFFFF0000u), 0.f);
    acc1.z += fmaxf(an1.z + __uint_as_float(bv.w << 16), 0.f);
    acc1.w += fmaxf(an1.w + __uint_as_float(bv.w & 0xFFFF0000u), 0.f);
  }

#pragma unroll
  for (int m = 8; m <= 32; m <<= 1) {
    acc0.x += __shfl_xor(acc0.x, m, 64);
    acc0.y += __shfl_xor(acc0.y, m, 64);
    acc0.z += __shfl_xor(acc0.z, m, 64);
    acc0.w += __shfl_xor(acc0.w, m, 64);
    acc1.x += __shfl_xor(acc1.x, m, 64);
    acc1.y += __shfl_xor(acc1.y, m, 64);
    acc1.z += __shfl_xor(acc1.z, m, 64);
    acc1.w += __shfl_xor(acc1.w, m, 64);
  }
  if (slot == 0) {
    float4* agg4 = (float4*)agg;
    agg4[(size_t)node * 16 + c8 * 2] = acc0;
    agg4[(size_t)node * 16 + c8 * 2 + 1] = acc1;
  }
}

// ============================ pooling + head ============================

__global__ void gstart_kernel(const int* __restrict__ batch, int* __restrict__ gstart) {
  int g = threadIdx.x;
  if (g > NG) return;
  int lo = 0, hi = NN;
  while (lo < hi) {
    int mid = (lo + hi) >> 1;
    if (batch[mid] < g) lo = mid + 1; else hi = mid;
  }
  gstart[g] = lo;
}

__global__ __launch_bounds__(256) void pool_kernel(const float* __restrict__ h,
                                                   const int* __restrict__ gstart,
                                                   float* __restrict__ pooled) {
  int g = blockIdx.x >> 2, q = blockIdx.x & 3;
  int lane = threadIdx.x & 63, w = threadIdx.x >> 6;
  int s = gstart[g], e = gstart[g + 1];
  int len = e - s;
  int qs = s + (len * q) / 4, qe = s + (len * (q + 1)) / 4;
  float a0 = 0.f, a1 = 0.f;
  int n = qs + w;
  for (; n + 4 < qe; n += 8) {
    a0 += h[(size_t)n * 64 + lane];
    a1 += h[(size_t)(n + 4) * 64 + lane];
  }
  for (; n < qe; n += 4) a0 += h[(size_t)n * 64 + lane];
  __shared__ float red[4][64];
  red[w][lane] = a0 + a1;
  __syncthreads();
  if (w == 0) {
    float sum = red[0][lane] + red[1][lane] + red[2][lane] + red[3][lane];
    atomicAdd(&pooled[g * 64 + lane], sum);
  }
}

__global__ void final_kernel(const float* __restrict__ pooled, const int* __restrict__ gstart,
                             const float* __restrict__ Wl, const float* __restrict__ bl,
                             float* __restrict__ out) {
  int idx = blockIdx.x * 256 + threadIdx.x;
  int g = idx >> 6, o = idx & 63;
  float inv = 1.f / fmaxf((float)(gstart[g + 1] - gstart[g]), 1.f);
  float acc = bl[o];
  for (int k = 0; k < 64; ++k) acc += pooled[g * 64 + k] * inv * Wl[k * 64 + o];
  out[idx] = acc;
}

// ============================ launch ============================

extern "C" void kernel_launch(void* const* d_in, const int* in_sizes, int n_in,
                              void* d_out, int out_size, void* d_ws, size_t ws_size,
                              hipStream_t stream) {
  const float* x = (const float*)d_in[0];
  const int* ei = (const int*)d_in[1];
  const int* batch = (const int*)d_in[2];
  const float* W1a = (const float*)d_in[3];
  const float* b1a = (const float*)d_in[4];
  const float* W2a = (const float*)d_in[5];
  const float* b2a = (const float*)d_in[6];
  const float* W1b = (const float*)d_in[7];
  const float* b1b = (const float*)d_in[8];
  const float* W2b = (const float*)d_in[9];
  const float* b2b = (const float*)d_in[10];
  const float* Wl = (const float*)d_in[11];
  const float* bl = (const float*)d_in[12];
  float* out = (float*)d_out;

  char* p = (char*)d_ws;
  auto alloc = [&](size_t bytes) {
    char* r = p;
    p += (bytes + 255) & ~(size_t)255;
    return r;
  };
  int* deg = (int*)alloc((NN + 1) * sizeof(int));
  int* rowptr = (int*)alloc((NN + 1) * sizeof(int));
  int* cursor = (int*)alloc(NN * sizeof(int));
  int* bsums = (int*)alloc(256 * sizeof(int));
  int* gstart = (int*)alloc((NG + 1) * sizeof(int));
  int* srcs = (int*)alloc((size_t)NE * sizeof(int));
  float* a_tab = (float*)alloc((size_t)NN * 64 * sizeof(float));
  unsigned int* b_tab = (unsigned int*)alloc((size_t)NN * 32 * sizeof(unsigned int));
  float* hbuf = (float*)alloc((size_t)NN * 64 * sizeof(float));
  float* pooled = (float*)alloc(NG * 64 * sizeof(float));

  hipMemsetAsync(deg, 0, (NN + 1) * sizeof(int), stream);
  hipMemsetAsync(pooled, 0, NG * 64 * sizeof(float), stream);

  hist_kernel<<<(NE + 255) / 256, 256, 0, stream>>>(ei, deg);
  scan1_kernel<<<196, 256, 0, stream>>>(deg, rowptr, bsums);
  scan2_kernel<<<1, 256, 0, stream>>>(bsums, 196);
  scan3_kernel<<<196, 256, 0, stream>>>(rowptr, bsums, cursor);
  scatter_xcd<<<1024, 256, 0, stream>>>(ei, cursor, srcs);
  gstart_kernel<<<1, 128, 0, stream>>>(batch, gstart);

  int tb = (NN + 127) / 128;  // 391
  // layer 1
  transform_dual<<<tb, 128, 0, stream>>>(x, W1a, a_tab, b_tab);
  edge_agg<<<(NN + 3) / 4, 256, 0, stream>>>(a_tab, b_tab, rowptr, srcs, b1a, hbuf);
  // fused: layer1 single + layer2 dual (h1 never hits memory)
  transform_fused<<<tb, 128, 0, stream>>>(hbuf, W2a, b2a, deg, W1b, a_tab, b_tab);
  edge_agg<<<(NN + 3) / 4, 256, 0, stream>>>(a_tab, b_tab, rowptr, srcs, b1b, hbuf);
  transform_single<<<tb, 128, 0, stream>>>(hbuf, W2b, b2b, deg, hbuf);
  // pool + head
  pool_kernel<<<NG * 4, 256, 0, stream>>>(hbuf, gstart, pooled);
  final_kernel<<<16, 256, 0, stream>>>(pooled, gstart, Wl, bl, out);
}

// Round 6
// 210.691 us; speedup vs baseline: 1.7503x; 1.7503x over previous
//
#include <hip/hip_runtime.h>

#define NN 50000
#define NE 800000
#define NG 64
#define DPART (NN / 8)

typedef float f32x4 __attribute__((ext_vector_type(4)));
typedef short bf16x8 __attribute__((ext_vector_type(8)));
typedef unsigned short ushort_t;

__device__ __forceinline__ ushort_t f2bf(float x) {
  unsigned int u = __float_as_uint(x);
  u = (u + 0x7FFFu + ((u >> 16) & 1u)) >> 16;
  return (ushort_t)u;
}
__device__ __forceinline__ unsigned int bfpack2(float lo, float hi) {
  return (unsigned int)f2bf(lo) | ((unsigned int)f2bf(hi) << 16);
}
__device__ __forceinline__ float4 add4(float4 a, float4 b) {
  return make_float4(a.x + b.x, a.y + b.y, a.z + b.z, a.w + b.w);
}
__device__ __forceinline__ f32x4 mfma16(bf16x8 a, bf16x8 b, f32x4 c) {
  return __builtin_amdgcn_mfma_f32_16x16x32_bf16(a, b, c, 0, 0, 0);
}

// ============================ CSR build ============================

__global__ void hist_kernel(const int* __restrict__ ei, int* __restrict__ deg) {
  int e = blockIdx.x * blockDim.x + threadIdx.x;
  if (e < NE) atomicAdd(&deg[ei[NE + e]], 1);
}

__global__ void scan1_kernel(const int* __restrict__ deg, int* __restrict__ rowptr,
                             int* __restrict__ bsums) {
  __shared__ int tile[256];
  int t = threadIdx.x, gid = blockIdx.x * 256 + t;
  int v = (gid < NN) ? deg[gid] : 0;
  tile[t] = v;
  __syncthreads();
  for (int off = 1; off < 256; off <<= 1) {
    int u = (t >= off) ? tile[t - off] : 0;
    __syncthreads();
    tile[t] += u;
    __syncthreads();
  }
  if (gid < NN) rowptr[gid] = tile[t] - v;
  if (t == 255) bsums[blockIdx.x] = tile[t];
}

__global__ void scan2_kernel(int* __restrict__ bsums, int nb) {
  __shared__ int tile[256];
  int t = threadIdx.x;
  int v = (t < nb) ? bsums[t] : 0;
  tile[t] = v;
  __syncthreads();
  for (int off = 1; off < 256; off <<= 1) {
    int u = (t >= off) ? tile[t - off] : 0;
    __syncthreads();
    tile[t] += u;
    __syncthreads();
  }
  if (t < nb) bsums[t] = tile[t] - v;
}

__global__ void scan3_kernel(int* __restrict__ rowptr, const int* __restrict__ bsums,
                             int* __restrict__ cursor) {
  int gid = blockIdx.x * 256 + threadIdx.x;
  if (gid < NN) {
    int r = rowptr[gid] + bsums[blockIdx.x];
    rowptr[gid] = r;
    cursor[gid] = r;
  } else if (gid == NN) {
    rowptr[NN] = NE;
  }
}

__global__ __launch_bounds__(256) void scatter_xcd(const int* __restrict__ ei,
                                                   int* __restrict__ cursor,
                                                   int* __restrict__ srcs) {
  int g = blockIdx.x & 7;
  int bid = blockIdx.x >> 3;
  int nb = gridDim.x >> 3;
  int lo = g * DPART, hi = lo + DPART;
  int stride = nb * 256;
  for (int e = bid * 256 + threadIdx.x; e < NE; e += stride) {
    int d = ei[NE + e];
    if (d >= lo && d < hi) {
      int pos = atomicAdd(&cursor[d], 1);
      srcs[pos] = ei[e];
    }
  }
}

// ============================ MFMA node GEMMs ============================
// Fragment conventions (16x16x32 bf16):
//   A: row = lane&15, k = (lane>>4)*8 + j          (8 bf16 / lane)
//   B: col = lane&15, k = (lane>>4)*8 + j
//   D: col = lane&15, row = (lane>>4)*4 + reg      (4 f32 / lane)
// A-tiles staged in LDS with byte-XOR swizzle ((row&7)<<4) to kill the
// 128B-row-stride bank conflict; B (weights) staged in frag-order so each
// frag is one contiguous ds_read_b128 per lane.

// dual: a_tab[n][c] = feat@W[:64] (f32); b_tab[n][c] = feat@W[64:] (bf16)
__global__ __launch_bounds__(256) void transform_dual(const float* __restrict__ feat,
                                                      const float* __restrict__ W,
                                                      float* __restrict__ a_tab,
                                                      ushort_t* __restrict__ b_tab) {
  __shared__ ushort_t wl[16 * 64 * 8];  // 16KB: frag f=ct*2+kh, 64 lanes, 8 elems
  __shared__ ushort_t xs[64 * 64];      // 8KB, swizzled
  int t = threadIdx.x;
  int nbase = blockIdx.x * 64;

  for (int i = t; i < 8192; i += 256) {
    int c = i & 127, k = i >> 6;  // note: i in [0,8192): c128 = i&127, k = i>>7
    c = i & 127; k = i >> 7;
    float v = W[((c >> 6) * 64 + k) * 64 + (c & 63)];
    int ct = c >> 4, lane = (c & 15) + ((k >> 3) & 3) * 16, kh = k >> 5;
    wl[((ct * 2 + kh) * 64 + lane) * 8 + (k & 7)] = f2bf(v);
  }
  {
    const float4* f4 = (const float4*)feat;
    uint2* x2 = (uint2*)xs;
    for (int i = t; i < 1024; i += 256) {
      int ni = i >> 4, c4 = i & 15;
      int node = nbase + ni;
      float4 v = make_float4(0.f, 0.f, 0.f, 0.f);
      if (node < NN) v = f4[(size_t)nbase * 16 + i];
      uint2 pk;
      pk.x = bfpack2(v.x, v.y);
      pk.y = bfpack2(v.z, v.w);
      x2[(ni * 16 + c4) ^ ((ni & 7) << 1)] = pk;
    }
  }
  __syncthreads();

  int wv = t >> 6, lane = t & 63;
  int lrow = wv * 16 + (lane & 15);
  const bf16x8* xf = (const bf16x8*)xs;
  bf16x8 a0 = xf[(lrow * 8 + (lane >> 4)) ^ (lrow & 7)];
  bf16x8 a1 = xf[(lrow * 8 + 4 + (lane >> 4)) ^ (lrow & 7)];
  const bf16x8* wf = (const bf16x8*)wl;

  f32x4 acc[8];
#pragma unroll
  for (int ct = 0; ct < 8; ++ct) {
    f32x4 c = {0.f, 0.f, 0.f, 0.f};
    c = mfma16(a0, wf[(ct * 2 + 0) * 64 + lane], c);
    c = mfma16(a1, wf[(ct * 2 + 1) * 64 + lane], c);
    acc[ct] = c;
  }

  int r0 = nbase + wv * 16 + (lane >> 4) * 4;
  int cl = lane & 15;
#pragma unroll
  for (int ct = 0; ct < 4; ++ct)
#pragma unroll
    for (int r = 0; r < 4; ++r) {
      int node = r0 + r;
      if (node < NN) a_tab[(size_t)node * 64 + ct * 16 + cl] = acc[ct][r];
    }
#pragma unroll
  for (int ct = 4; ct < 8; ++ct)
#pragma unroll
    for (int r = 0; r < 4; ++r) {
      int node = r0 + r;
      if (node < NN) b_tab[(size_t)node * 64 + (ct - 4) * 16 + cl] = f2bf(acc[ct][r]);
    }
}

// fused: h = relu(agg@W2 + cnt*b2) (regs+LDS only); a_tab/b_tab = h@W1 halves
__global__ __launch_bounds__(256) void transform_fused(const float* __restrict__ agg,
                                                       const float* __restrict__ W2,
                                                       const float* __restrict__ b2,
                                                       const int* __restrict__ deg,
                                                       const float* __restrict__ W1,
                                                       float* __restrict__ a_tab,
                                                       ushort_t* __restrict__ b_tab) {
  __shared__ ushort_t w2l[8 * 64 * 8];   // 8KB
  __shared__ ushort_t w1l[16 * 64 * 8];  // 16KB
  __shared__ ushort_t xs[64 * 64];       // 8KB
  __shared__ ushort_t hs[64 * 64];       // 8KB
  int t = threadIdx.x;
  int nbase = blockIdx.x * 64;

  for (int i = t; i < 4096; i += 256) {
    int c = i & 63, k = i >> 6;
    float v = W2[k * 64 + c];
    int ct = c >> 4, lane = (c & 15) + ((k >> 3) & 3) * 16, kh = k >> 5;
    w2l[((ct * 2 + kh) * 64 + lane) * 8 + (k & 7)] = f2bf(v);
  }
  for (int i = t; i < 8192; i += 256) {
    int c = i & 127, k = i >> 7;
    float v = W1[((c >> 6) * 64 + k) * 64 + (c & 63)];
    int ct = c >> 4, lane = (c & 15) + ((k >> 3) & 3) * 16, kh = k >> 5;
    w1l[((ct * 2 + kh) * 64 + lane) * 8 + (k & 7)] = f2bf(v);
  }
  {
    const float4* f4 = (const float4*)agg;
    uint2* x2 = (uint2*)xs;
    for (int i = t; i < 1024; i += 256) {
      int ni = i >> 4, c4 = i & 15;
      int node = nbase + ni;
      float4 v = make_float4(0.f, 0.f, 0.f, 0.f);
      if (node < NN) v = f4[(size_t)nbase * 16 + i];
      uint2 pk;
      pk.x = bfpack2(v.x, v.y);
      pk.y = bfpack2(v.z, v.w);
      x2[(ni * 16 + c4) ^ ((ni & 7) << 1)] = pk;
    }
  }
  __syncthreads();

  int wv = t >> 6, lane = t & 63;
  int lrow = wv * 16 + (lane & 15);
  const bf16x8* xf = (const bf16x8*)xs;
  bf16x8 a0 = xf[(lrow * 8 + (lane >> 4)) ^ (lrow & 7)];
  bf16x8 a1 = xf[(lrow * 8 + 4 + (lane >> 4)) ^ (lrow & 7)];
  const bf16x8* w2f = (const bf16x8*)w2l;

  f32x4 hacc[4];
#pragma unroll
  for (int ct = 0; ct < 4; ++ct) {
    f32x4 c = {0.f, 0.f, 0.f, 0.f};
    c = mfma16(a0, w2f[(ct * 2 + 0) * 64 + lane], c);
    c = mfma16(a1, w2f[(ct * 2 + 1) * 64 + lane], c);
    hacc[ct] = c;
  }

  int r0 = nbase + wv * 16 + (lane >> 4) * 4;
  int lr0 = wv * 16 + (lane >> 4) * 4;
  int cl = lane & 15;
  float cnt[4];
#pragma unroll
  for (int r = 0; r < 4; ++r) {
    int node = r0 + r;
    cnt[r] = (node < NN) ? (float)(deg[node] + 1) : 0.f;
  }
#pragma unroll
  for (int ct = 0; ct < 4; ++ct) {
    float bv = b2[ct * 16 + cl];
#pragma unroll
    for (int r = 0; r < 4; ++r) {
      float h = fmaxf(hacc[ct][r] + cnt[r] * bv, 0.f);
      int lr = lr0 + r;
      hs[(lr * 64 + ct * 16 + cl) ^ ((lr & 7) << 3)] = f2bf(h);
    }
  }
  __syncthreads();

  const bf16x8* hf = (const bf16x8*)hs;
  bf16x8 h0 = hf[(lrow * 8 + (lane >> 4)) ^ (lrow & 7)];
  bf16x8 h1 = hf[(lrow * 8 + 4 + (lane >> 4)) ^ (lrow & 7)];
  const bf16x8* w1f = (const bf16x8*)w1l;

  f32x4 acc[8];
#pragma unroll
  for (int ct = 0; ct < 8; ++ct) {
    f32x4 c = {0.f, 0.f, 0.f, 0.f};
    c = mfma16(h0, w1f[(ct * 2 + 0) * 64 + lane], c);
    c = mfma16(h1, w1f[(ct * 2 + 1) * 64 + lane], c);
    acc[ct] = c;
  }
#pragma unroll
  for (int ct = 0; ct < 4; ++ct)
#pragma unroll
    for (int r = 0; r < 4; ++r) {
      int node = r0 + r;
      if (node < NN) a_tab[(size_t)node * 64 + ct * 16 + cl] = acc[ct][r];
    }
#pragma unroll
  for (int ct = 4; ct < 8; ++ct)
#pragma unroll
    for (int r = 0; r < 4; ++r) {
      int node = r0 + r;
      if (node < NN) b_tab[(size_t)node * 64 + (ct - 4) * 16 + cl] = f2bf(acc[ct][r]);
    }
}

// single: out = relu(agg@W2 + cnt*b2); in-place safe (tile staged before writes)
__global__ __launch_bounds__(256) void transform_single(const float* __restrict__ agg,
                                                        const float* __restrict__ W2,
                                                        const float* __restrict__ b2,
                                                        const int* __restrict__ deg,
                                                        float* __restrict__ out) {
  __shared__ ushort_t w2l[8 * 64 * 8];
  __shared__ ushort_t xs[64 * 64];
  int t = threadIdx.x;
  int nbase = blockIdx.x * 64;

  for (int i = t; i < 4096; i += 256) {
    int c = i & 63, k = i >> 6;
    float v = W2[k * 64 + c];
    int ct = c >> 4, lane = (c & 15) + ((k >> 3) & 3) * 16, kh = k >> 5;
    w2l[((ct * 2 + kh) * 64 + lane) * 8 + (k & 7)] = f2bf(v);
  }
  {
    const float4* f4 = (const float4*)agg;
    uint2* x2 = (uint2*)xs;
    for (int i = t; i < 1024; i += 256) {
      int ni = i >> 4, c4 = i & 15;
      int node = nbase + ni;
      float4 v = make_float4(0.f, 0.f, 0.f, 0.f);
      if (node < NN) v = f4[(size_t)nbase * 16 + i];
      uint2 pk;
      pk.x = bfpack2(v.x, v.y);
      pk.y = bfpack2(v.z, v.w);
      x2[(ni * 16 + c4) ^ ((ni & 7) << 1)] = pk;
    }
  }
  __syncthreads();

  int wv = t >> 6, lane = t & 63;
  int lrow = wv * 16 + (lane & 15);
  const bf16x8* xf = (const bf16x8*)xs;
  bf16x8 a0 = xf[(lrow * 8 + (lane >> 4)) ^ (lrow & 7)];
  bf16x8 a1 = xf[(lrow * 8 + 4 + (lane >> 4)) ^ (lrow & 7)];
  const bf16x8* w2f = (const bf16x8*)w2l;

  f32x4 acc[4];
#pragma unroll
  for (int ct = 0; ct < 4; ++ct) {
    f32x4 c = {0.f, 0.f, 0.f, 0.f};
    c = mfma16(a0, w2f[(ct * 2 + 0) * 64 + lane], c);
    c = mfma16(a1, w2f[(ct * 2 + 1) * 64 + lane], c);
    acc[ct] = c;
  }

  int r0 = nbase + wv * 16 + (lane >> 4) * 4;
  int cl = lane & 15;
  float cnt[4];
#pragma unroll
  for (int r = 0; r < 4; ++r) {
    int node = r0 + r;
    cnt[r] = (node < NN) ? (float)(deg[node] + 1) : 0.f;
  }
#pragma unroll
  for (int ct = 0; ct < 4; ++ct) {
    float bv = b2[ct * 16 + cl];
#pragma unroll
    for (int r = 0; r < 4; ++r) {
      int node = r0 + r;
      if (node < NN)
        out[(size_t)node * 64 + ct * 16 + cl] = fmaxf(acc[ct][r] + cnt[r] * bv, 0.f);
    }
  }
}

// ============================ edge aggregation ============================
// agg[n][c] = sum over in-edges+self of relu(a[n][c]+b1[c]+b_bf16[src][c])
__global__ __launch_bounds__(256) void edge_agg(const float* __restrict__ a_tab,
                                                const ushort_t* __restrict__ b_tab,
                                                const int* __restrict__ rowptr,
                                                const int* __restrict__ srcs,
                                                const float* __restrict__ b1,
                                                float* __restrict__ agg) {
  int node = blockIdx.x * 4 + (threadIdx.x >> 6);
  if (node >= NN) return;
  int lane = threadIdx.x & 63;
  int slot = lane >> 3;
  int c8 = lane & 7;

  const float4* a4 = (const float4*)a_tab;
  const float4* b14 = (const float4*)b1;
  const uint4* bt = (const uint4*)b_tab;

  float4 an0 = add4(a4[(size_t)node * 16 + c8 * 2], b14[c8 * 2]);
  float4 an1 = add4(a4[(size_t)node * 16 + c8 * 2 + 1], b14[c8 * 2 + 1]);

  float4 acc0 = make_float4(0.f, 0.f, 0.f, 0.f);
  float4 acc1 = make_float4(0.f, 0.f, 0.f, 0.f);

  if (slot == 0) {
    uint4 bv = bt[(size_t)node * 8 + c8];
    acc0.x = fmaxf(an0.x + __uint_as_float(bv.x << 16), 0.f);
    acc0.y = fmaxf(an0.y + __uint_as_float(bv.x & 0xFFFF0000u), 0.f);
    acc0.z = fmaxf(an0.z + __uint_as_float(bv.y << 16), 0.f);
    acc0.w = fmaxf(an0.w + __uint_as_float(bv.y & 0xFFFF0000u), 0.f);
    acc1.x = fmaxf(an1.x + __uint_as_float(bv.z << 16), 0.f);
    acc1.y = fmaxf(an1.y + __uint_as_float(bv.z & 0xFFFF0000u), 0.f);
    acc1.z = fmaxf(an1.z + __uint_as_float(bv.w << 16), 0.f);
    acc1.w = fmaxf(an1.w + __uint_as_float(bv.w & 0xFFFF0000u), 0.f);
  }

  int s0 = rowptr[node], s1 = rowptr[node + 1];
  for (int e = s0 + slot; e < s1; e += 8) {
    int s = srcs[e];
    uint4 bv = bt[(size_t)s * 8 + c8];
    acc0.x += fmaxf(an0.x + __uint_as_float(bv.x << 16), 0.f);
    acc0.y += fmaxf(an0.y + __uint_as_float(bv.x & 0xFFFF0000u), 0.f);
    acc0.z += fmaxf(an0.z + __uint_as_float(bv.y << 16), 0.f);
    acc0.w += fmaxf(an0.w + __uint_as_float(bv.y & 0xFFFF0000u), 0.f);
    acc1.x += fmaxf(an1.x + __uint_as_float(bv.z << 16), 0.f);
    acc1.y += fmaxf(an1.y + __uint_as_float(bv.z & 0xFFFF0000u), 0.f);
    acc1.z += fmaxf(an1.z + __uint_as_float(bv.w << 16), 0.f);
    acc1.w += fmaxf(an1.w + __uint_as_float(bv.w & 0xFFFF0000u), 0.f);
  }

#pragma unroll
  for (int m = 8; m <= 32; m <<= 1) {
    acc0.x += __shfl_xor(acc0.x, m, 64);
    acc0.y += __shfl_xor(acc0.y, m, 64);
    acc0.z += __shfl_xor(acc0.z, m, 64);
    acc0.w += __shfl_xor(acc0.w, m, 64);
    acc1.x += __shfl_xor(acc1.x, m, 64);
    acc1.y += __shfl_xor(acc1.y, m, 64);
    acc1.z += __shfl_xor(acc1.z, m, 64);
    acc1.w += __shfl_xor(acc1.w, m, 64);
  }
  if (slot == 0) {
    float4* agg4 = (float4*)agg;
    agg4[(size_t)node * 16 + c8 * 2] = acc0;
    agg4[(size_t)node * 16 + c8 * 2 + 1] = acc1;
  }
}

// ============================ pooling + head ============================

__global__ void gstart_kernel(const int* __restrict__ batch, int* __restrict__ gstart) {
  int g = threadIdx.x;
  if (g > NG) return;
  int lo = 0, hi = NN;
  while (lo < hi) {
    int mid = (lo + hi) >> 1;
    if (batch[mid] < g) lo = mid + 1; else hi = mid;
  }
  gstart[g] = lo;
}

__global__ __launch_bounds__(256) void pool_kernel(const float* __restrict__ h,
                                                   const int* __restrict__ gstart,
                                                   float* __restrict__ pooled) {
  int g = blockIdx.x >> 2, q = blockIdx.x & 3;
  int lane = threadIdx.x & 63, w = threadIdx.x >> 6;
  int s = gstart[g], e = gstart[g + 1];
  int len = e - s;
  int qs = s + (len * q) / 4, qe = s + (len * (q + 1)) / 4;
  float a0 = 0.f, a1 = 0.f;
  int n = qs + w;
  for (; n + 4 < qe; n += 8) {
    a0 += h[(size_t)n * 64 + lane];
    a1 += h[(size_t)(n + 4) * 64 + lane];
  }
  for (; n < qe; n += 4) a0 += h[(size_t)n * 64 + lane];
  __shared__ float red[4][64];
  red[w][lane] = a0 + a1;
  __syncthreads();
  if (w == 0) {
    float sum = red[0][lane] + red[1][lane] + red[2][lane] + red[3][lane];
    atomicAdd(&pooled[g * 64 + lane], sum);
  }
}

__global__ void final_kernel(const float* __restrict__ pooled, const int* __restrict__ gstart,
                             const float* __restrict__ Wl, const float* __restrict__ bl,
                             float* __restrict__ out) {
  int idx = blockIdx.x * 256 + threadIdx.x;
  int g = idx >> 6, o = idx & 63;
  float inv = 1.f / fmaxf((float)(gstart[g + 1] - gstart[g]), 1.f);
  float acc = bl[o];
  for (int k = 0; k < 64; ++k) acc += pooled[g * 64 + k] * inv * Wl[k * 64 + o];
  out[idx] = acc;
}

// ============================ launch ============================

extern "C" void kernel_launch(void* const* d_in, const int* in_sizes, int n_in,
                              void* d_out, int out_size, void* d_ws, size_t ws_size,
                              hipStream_t stream) {
  const float* x = (const float*)d_in[0];
  const int* ei = (const int*)d_in[1];
  const int* batch = (const int*)d_in[2];
  const float* W1a = (const float*)d_in[3];
  const float* b1a = (const float*)d_in[4];
  const float* W2a = (const float*)d_in[5];
  const float* b2a = (const float*)d_in[6];
  const float* W1b = (const float*)d_in[7];
  const float* b1b = (const float*)d_in[8];
  const float* W2b = (const float*)d_in[9];
  const float* b2b = (const float*)d_in[10];
  const float* Wl = (const float*)d_in[11];
  const float* bl = (const float*)d_in[12];
  float* out = (float*)d_out;

  char* p = (char*)d_ws;
  auto alloc = [&](size_t bytes) {
    char* r = p;
    p += (bytes + 255) & ~(size_t)255;
    return r;
  };
  int* deg = (int*)alloc((NN + 1) * sizeof(int));
  int* rowptr = (int*)alloc((NN + 1) * sizeof(int));
  int* cursor = (int*)alloc(NN * sizeof(int));
  int* bsums = (int*)alloc(256 * sizeof(int));
  int* gstart = (int*)alloc((NG + 1) * sizeof(int));
  int* srcs = (int*)alloc((size_t)NE * sizeof(int));
  float* a_tab = (float*)alloc((size_t)NN * 64 * sizeof(float));
  ushort_t* b_tab = (ushort_t*)alloc((size_t)NN * 64 * sizeof(ushort_t));
  float* hbuf = (float*)alloc((size_t)NN * 64 * sizeof(float));
  float* pooled = (float*)alloc(NG * 64 * sizeof(float));

  hipMemsetAsync(deg, 0, (NN + 1) * sizeof(int), stream);
  hipMemsetAsync(pooled, 0, NG * 64 * sizeof(float), stream);

  hist_kernel<<<(NE + 255) / 256, 256, 0, stream>>>(ei, deg);
  scan1_kernel<<<196, 256, 0, stream>>>(deg, rowptr, bsums);
  scan2_kernel<<<1, 256, 0, stream>>>(bsums, 196);
  scan3_kernel<<<196, 256, 0, stream>>>(rowptr, bsums, cursor);
  scatter_xcd<<<1024, 256, 0, stream>>>(ei, cursor, srcs);
  gstart_kernel<<<1, 128, 0, stream>>>(batch, gstart);

  int tb = (NN + 63) / 64;  // 782
  // layer 1
  transform_dual<<<tb, 256, 0, stream>>>(x, W1a, a_tab, b_tab);
  edge_agg<<<(NN + 3) / 4, 256, 0, stream>>>(a_tab, b_tab, rowptr, srcs, b1a, hbuf);
  // fused: layer1 epilogue + layer2 tables (h1 stays on-chip)
  transform_fused<<<tb, 256, 0, stream>>>(hbuf, W2a, b2a, deg, W1b, a_tab, b_tab);
  edge_agg<<<(NN + 3) / 4, 256, 0, stream>>>(a_tab, b_tab, rowptr, srcs, b1b, hbuf);
  transform_single<<<tb, 256, 0, stream>>>(hbuf, W2b, b2b, deg, hbuf);
  // pool + head
  pool_kernel<<<NG * 4, 256, 0, stream>>>(hbuf, gstart, pooled);
  final_kernel<<<16, 256, 0, stream>>>(pooled, gstart, Wl, bl, out);
}